// Round 3
// baseline (7106.679 us; speedup 1.0000x reference)
//
#include <hip/hip_runtime.h>

#define T_ 2048
#define H_ 1024
#define S_ 1024
#define V_ 32000
#define I_ 2048
#define NHD 1024   // NH*HD
#define KVD 512    // NKV*HD

typedef unsigned short u16;
typedef unsigned int u32;
typedef __attribute__((ext_vector_type(8))) short s16x8;
typedef __attribute__((ext_vector_type(4))) float f32x4;

__device__ __forceinline__ u16 f2b(float f){ u32 x=__builtin_bit_cast(u32,f); return (u16)((x+0x7fffu+((x>>16)&1u))>>16); }
__device__ __forceinline__ float b2f(u16 u){ return __builtin_bit_cast(float,(u32)u<<16); }
__device__ __forceinline__ u32 pk2(float lo,float hi){ return (u32)f2b(lo)|((u32)f2b(hi)<<16); }
__device__ __forceinline__ void sp2(float a,float b,u32&h,u32&l){
  u16 ha=f2b(a), hb=f2b(b);
  float ra=a-b2f(ha), rb=b-b2f(hb);          // Sterbenz: residual exact
  h=(u32)ha|((u32)hb<<16); l=(u32)f2b(ra)|((u32)f2b(rb)<<16);
}
__device__ __forceinline__ float wsum(float v){ for(int o=32;o;o>>=1) v+=__shfl_xor(v,o); return v; }
__device__ __forceinline__ float wmax(float v){ for(int o=32;o;o>>=1) v=fmaxf(v,__shfl_xor(v,o)); return v; }

// ---------------- embedding gather ----------------
__global__ void k_embed(const int* __restrict__ ids, const float* __restrict__ emb, float* __restrict__ h){
  int t = blockIdx.x;
  long src = (long)ids[t]*H_;
  ((float4*)(h + (long)t*H_))[threadIdx.x] = ((const float4*)(emb+src))[threadIdx.x];
}

// ---------------- rmsnorm: fp32 -> fp32 ----------------
__global__ void k_rms(const float* __restrict__ h, const float* __restrict__ w, float* __restrict__ out){
  int wid = threadIdx.x>>6, lane = threadIdx.x&63;
  int t = blockIdx.x*4 + wid;
  const float* row = h + (long)t*H_;
  float v[16]; float ss=0.f;
  #pragma unroll
  for(int j=0;j<16;j++){ v[j]=row[j*64+lane]; ss += v[j]*v[j]; }
  ss = wsum(ss);
  float rstd = rsqrtf(ss/(float)H_ + 1e-6f);
  float* orow = out + (long)t*H_;
  #pragma unroll
  for(int j=0;j<16;j++) orow[j*64+lane] = v[j]*rstd*w[j*64+lane];
}

// ---------------- router (all fp32) ----------------
__global__ void k_router(const float* __restrict__ h, const float* __restrict__ lw,
                         const float* __restrict__ gate, float* __restrict__ comb){
  int wid = threadIdx.x>>6, lane = threadIdx.x&63;
  int t = blockIdx.x*4+wid;
  const float* row = h + (long)t*H_;
  float v[16]; float ss=0.f;
  #pragma unroll
  for(int j=0;j<16;j++){ v[j]=row[j*64+lane]; ss+=v[j]*v[j]; }
  ss = wsum(ss);
  float rstd = rsqrtf(ss/(float)H_+1e-6f);
  float a0=0,a1=0,a2=0,a3=0;
  #pragma unroll
  for(int j=0;j<16;j++){
    int idx=j*64+lane;
    float xv = v[j]*rstd*lw[idx];
    float4 g4 = ((const float4*)gate)[idx];
    a0 += xv*g4.x; a1 += xv*g4.y; a2 += xv*g4.z; a3 += xv*g4.w;
  }
  a0=wsum(a0); a1=wsum(a1); a2=wsum(a2); a3=wsum(a3);
  if(lane==0){
    float p[4]={a0,a1,a2,a3};
    float m = fmaxf(fmaxf(p[0],p[1]),fmaxf(p[2],p[3]));
    float s=0; for(int e=0;e<4;e++){ p[e]=__expf(p[e]-m); s+=p[e]; }
    for(int e=0;e<4;e++) p[e]/=s;
    int i1=0; for(int e=1;e<4;e++) if(p[e]>p[i1]) i1=e;
    int i2=-1; for(int e=0;e<4;e++){ if(e==i1) continue; if(i2<0||p[e]>p[i2]) i2=e; }
    float* c = comb + (long)t*4;
    for(int e=0;e<4;e++) c[e] = (e==i1||e==i2)? p[e] : 0.f;
  }
}

// ---------------- causal row softmax (in-place, fp32) ----------------
__global__ void k_softmax(float* __restrict__ sc){
  int wid=threadIdx.x>>6, lane=threadIdx.x&63;
  int r = blockIdx.x*4+wid;
  float* row = sc + (long)blockIdx.y*((long)S_*S_) + (long)r*S_;
  float e[16]; float mx=-3.4e38f;
  #pragma unroll
  for(int j=0;j<16;j++){ int idx=j*64+lane; float vv=row[idx]; vv = (idx<=r)? vv : -3.4e38f; e[j]=vv; mx=fmaxf(mx,vv); }
  mx = wmax(mx);
  float s=0.f;
  #pragma unroll
  for(int j=0;j<16;j++){ int idx=j*64+lane; float vv = (idx<=r)? __expf(e[j]-mx) : 0.f; e[j]=vv; s+=vv; }
  s = wsum(s);
  float inv = 1.f/s;
  #pragma unroll
  for(int j=0;j<16;j++) row[j*64+lane] = e[j]*inv;
}

// ---------------- transpose+split: fp32 [R][C] -> bf16 hi(+lo) [C][R] ----------------
__global__ void k_transpose(const float* __restrict__ in, u16* __restrict__ hi, u16* __restrict__ lo,
                            int R, int C, long zi, long zo){
  __shared__ float tile[32][33];
  in += (long)blockIdx.z*zi; hi += (long)blockIdx.z*zo; if(lo) lo += (long)blockIdx.z*zo;
  int c0 = blockIdx.x*32, r0 = blockIdx.y*32;
  int tx = threadIdx.x, ty = threadIdx.y;
  #pragma unroll
  for(int i=0;i<4;i++) tile[ty+8*i][tx] = in[(long)(r0+ty+8*i)*C + c0+tx];
  __syncthreads();
  #pragma unroll
  for(int i=0;i<4;i++){
    int cc=ty+8*i; float v = tile[tx][cc];
    u16 hv = f2b(v);
    long idx = (long)(c0+cc)*R + r0+tx;
    hi[idx] = hv;
    if(lo) lo[idx] = f2b(v - b2f(hv));
  }
}

// ---------------- elementwise split fp32 -> hi/lo bf16 planes ----------------
__global__ void k_split(const float* __restrict__ in, u16* __restrict__ hi, u16* __restrict__ lo){
  long i = ((long)blockIdx.x*blockDim.x + threadIdx.x)*4;
  float4 v = *(const float4*)(in+i);
  u16 h0=f2b(v.x),h1=f2b(v.y),h2=f2b(v.z),h3=f2b(v.w);
  ushort4 H; H.x=h0; H.y=h1; H.z=h2; H.w=h3;
  ushort4 L; L.x=f2b(v.x-b2f(h0)); L.y=f2b(v.y-b2f(h1)); L.z=f2b(v.z-b2f(h2)); L.w=f2b(v.w-b2f(h3));
  *(ushort4*)(hi+i)=H; *(ushort4*)(lo+i)=L;
}

// ---------------- MFMA GEMM: C[M,N] = A[M,K](fp32) * B[N,K]^T ----------------
// SPL: bf16x2 split precision (A split on-the-fly, B hi/lo planes, 3 MFMAs)
// EPI: 1=store f32*scale, 2=f32 +=, 3=silu(acc)*U -> f32 (Cp aliases U),
//      4=f32 += comb[m,e]*acc, 5=store f32 transposed [b][col][tok]
// CM : 0=none, 1=skip blocks strictly above diagonal, 2=K-limit at m0+BM (causal PV)
template<int BM,int BN,int WM,int WN,bool SPL,int EPI,int CM>
__launch_bounds__(WM*WN*64)
__global__ void k_gemm(const float* __restrict__ Ap, const u16* __restrict__ Bhip,
                       const u16* __restrict__ Blop, void* __restrict__ Cp,
                       const void* __restrict__ auxp,
                       int Kdim, int lda, int ldb, int ldc,
                       long zA, long zB, int zBdiv, long zC,
                       float scale, int eidx)
{
  constexpr int NT = WM*WN*64;
  constexpr int BK = 32;
  constexpr int LK = BK+8;
  constexpr int WMT = BM/WM, WNT = BN/WN;
  constexpr int MF = WMT/16, NF = WNT/16;
  constexpr int ACH = (BM*BK)/(NT*8);
  constexpr int BCH = (BN*BK)/(NT*8);
  constexpr int PL = SPL?2:1;
  static_assert(ACH>=1 && BCH>=1, "staging chunks");
  __shared__ alignas(16) u16 As[PL*BM*LK];
  __shared__ alignas(16) u16 Bs[PL*BN*LK];
  const int m0 = blockIdx.x*BM, n0 = blockIdx.y*BN;
  if (CM==1 && n0 > m0) return;
  const int z = blockIdx.z;
  const int tid = threadIdx.x, lane = tid&63, w = tid>>6;
  const int wr = w/WN, wc = w%WN;
  const float* Af = Ap + (long)z*zA;
  const u16*  Bh  = Bhip + (long)(z/zBdiv)*zB;
  const u16*  Bl  = SPL ? (Blop + (long)(z/zBdiv)*zB) : (const u16*)nullptr;

  f32x4 acc[MF][NF];
  #pragma unroll
  for(int i=0;i<MF;i++)
    #pragma unroll
    for(int j=0;j<NF;j++){ f32x4 zv={0.f,0.f,0.f,0.f}; acc[i][j]=zv; }

  int ktend = Kdim/BK;
  if (CM==2){ int lim=(m0+BM)/BK; if(lim<ktend) ktend=lim; }

  for(int kt=0;kt<ktend;kt++){
    const int k0 = kt*BK;
    uint4 avh[ACH], avl[ACH], bvh[BCH], bvl[BCH];
    #pragma unroll
    for(int s=0;s<ACH;s++){
      int c = s*NT+tid; int row=c>>2; int kc=(c&3)*8;
      const float* pA = Af + (long)(m0+row)*lda + k0+kc;
      float4 X=*(const float4*)pA, Y=*(const float4*)(pA+4);
      if constexpr (SPL){
        sp2(X.x,X.y,avh[s].x,avl[s].x); sp2(X.z,X.w,avh[s].y,avl[s].y);
        sp2(Y.x,Y.y,avh[s].z,avl[s].z); sp2(Y.z,Y.w,avh[s].w,avl[s].w);
      } else {
        avh[s].x=pk2(X.x,X.y); avh[s].y=pk2(X.z,X.w); avh[s].z=pk2(Y.x,Y.y); avh[s].w=pk2(Y.z,Y.w);
      }
    }
    #pragma unroll
    for(int s=0;s<BCH;s++){
      int c = s*NT+tid; int row=c>>2; int kc=(c&3)*8;
      bvh[s] = *(const uint4*)(Bh + (long)(n0+row)*ldb + k0+kc);
      if constexpr (SPL) bvl[s] = *(const uint4*)(Bl + (long)(n0+row)*ldb + k0+kc);
    }
    __syncthreads();
    #pragma unroll
    for(int s=0;s<ACH;s++){ int c=s*NT+tid; int row=c>>2; int kc=(c&3)*8;
      *(uint4*)&As[row*LK+kc] = avh[s];
      if constexpr (SPL) *(uint4*)&As[BM*LK + row*LK+kc] = avl[s]; }
    #pragma unroll
    for(int s=0;s<BCH;s++){ int c=s*NT+tid; int row=c>>2; int kc=(c&3)*8;
      *(uint4*)&Bs[row*LK+kc] = bvh[s];
      if constexpr (SPL) *(uint4*)&Bs[BN*LK + row*LK+kc] = bvl[s]; }
    __syncthreads();
    s16x8 ah[MF], bh[NF], al[MF], bl[NF];
    const int rA = lane&15, kg=(lane>>4)*8;
    #pragma unroll
    for(int i=0;i<MF;i++){
      ah[i]=*(const s16x8*)&As[(wr*WMT+i*16+rA)*LK+kg];
      if constexpr (SPL) al[i]=*(const s16x8*)&As[BM*LK+(wr*WMT+i*16+rA)*LK+kg];
    }
    #pragma unroll
    for(int j=0;j<NF;j++){
      bh[j]=*(const s16x8*)&Bs[(wc*WNT+j*16+rA)*LK+kg];
      if constexpr (SPL) bl[j]=*(const s16x8*)&Bs[BN*LK+(wc*WNT+j*16+rA)*LK+kg];
    }
    #pragma unroll
    for(int i=0;i<MF;i++)
      #pragma unroll
      for(int j=0;j<NF;j++){
        acc[i][j]=__builtin_amdgcn_mfma_f32_16x16x32_bf16(ah[i],bh[j],acc[i][j],0,0,0);
        if constexpr (SPL){
          acc[i][j]=__builtin_amdgcn_mfma_f32_16x16x32_bf16(ah[i],bl[j],acc[i][j],0,0,0);
          acc[i][j]=__builtin_amdgcn_mfma_f32_16x16x32_bf16(al[i],bh[j],acc[i][j],0,0,0);
        }
      }
  }

  #pragma unroll
  for(int i=0;i<MF;i++){
    #pragma unroll
    for(int j=0;j<NF;j++){
      const int gm0 = m0 + wr*WMT + i*16 + ((lane>>4)<<2);
      const int gn  = n0 + wc*WNT + j*16 + (lane&15);
      #pragma unroll
      for(int r=0;r<4;r++){
        const int gm = gm0+r;
        const float v = acc[i][j][r];
        if constexpr (EPI==1){
          ((float*)Cp + (long)z*zC)[(long)gm*ldc+gn] = v*scale;
        } else if constexpr (EPI==2){
          float* C = (float*)Cp; C[(long)gm*ldc+gn] += v;
        } else if constexpr (EPI==3){
          const float* U = (const float*)auxp;
          float sg = v/(1.f+__expf(-v));
          ((float*)Cp)[(long)gm*ldc+gn] = sg*U[(long)gm*ldc+gn];
        } else if constexpr (EPI==4){
          const float* cb = (const float*)auxp;
          ((float*)Cp)[(long)gm*ldc+gn] += cb[gm*4+eidx]*v;
        } else if constexpr (EPI==5){
          ((float*)Cp)[((long)(gm>>10)<<19) + (long)gn*S_ + (gm&1023)] = v;
        }
      }
    }
  }
}

extern "C" void kernel_launch(void* const* d_in, const int* in_sizes, int n_in,
                              void* d_out, int out_size, void* d_ws, size_t ws_size,
                              hipStream_t stream)
{
  (void)in_sizes; (void)n_in; (void)out_size;
  const int*   ids   = (const int*)d_in[0];
  const float* emb   = (const float*)d_in[1];
  const float* Wq    = (const float*)d_in[2];
  const float* Wk    = (const float*)d_in[3];
  const float* Wv    = (const float*)d_in[4];
  const float* Wo    = (const float*)d_in[5];
  const float* ln1   = (const float*)d_in[6];
  const float* ln2   = (const float*)d_in[7];
  const float* gate  = (const float*)d_in[8];
  const float* Wg    = (const float*)d_in[9];
  const float* Wu    = (const float*)d_in[10];
  const float* Wd    = (const float*)d_in[11];
  const float* normw = (const float*)d_in[12];
  const float* lmh   = (const float*)d_in[13];

  char* p = (char*)d_ws;
  auto carve = [&](size_t bytes)->void*{ void* r=p; p += (bytes+255)&~(size_t)255; return r; };
  float* h    = (float*)carve((size_t)T_*H_*4);
  float* x    = (float*)carve((size_t)T_*H_*4);
  float* q    = (float*)carve((size_t)T_*NHD*4);
  float* kf   = (float*)carve((size_t)T_*KVD*4);
  u16*   khi  = (u16*)  carve((size_t)T_*KVD*2);
  u16*   klo  = (u16*)  carve((size_t)T_*KVD*2);
  float* vT   = (float*)carve((size_t)T_*KVD*4);
  u16*   vthi = (u16*)  carve((size_t)T_*KVD*2);
  u16*   vtlo = (u16*)  carve((size_t)T_*KVD*2);
  float* o    = (float*)carve((size_t)T_*NHD*4);
  float* sc   = (float*)carve((size_t)8*S_*S_*4);
  float* comb = (float*)carve((size_t)T_*4*4);
  float* gu   = (float*)carve((size_t)T_*I_*4);
  u16*   wp   = (u16*)  carve((size_t)56623104*2);   // weight hi/lo planes (also reused for lm_head)
  if ((size_t)(p - (char*)d_ws) > ws_size) return;

  u16 *WqTh = wp,            *WqTl = wp+1048576;
  u16 *WkTh = wp+2097152,    *WkTl = wp+2621440;
  u16 *WvTh = wp+3145728,    *WvTl = wp+3670016;
  u16 *WoTh = wp+4194304,    *WoTl = wp+5242880;
  u16 *WgTh = wp+6291456,    *WgTl = wp+14680064;
  u16 *WuTh = wp+23068672,   *WuTl = wp+31457280;
  u16 *WdTh = wp+39845888,   *WdTl = wp+48234496;

  dim3 tb(32,8);

  k_embed<<<T_,256,0,stream>>>(ids, emb, h);

  for(int l=0;l<4;l++){
    k_transpose<<<dim3(32,32),tb,0,stream>>>(Wq+(size_t)l*H_*NHD, WqTh, WqTl, H_, NHD, 0,0);
    k_transpose<<<dim3(16,32),tb,0,stream>>>(Wk+(size_t)l*H_*KVD, WkTh, WkTl, H_, KVD, 0,0);
    k_transpose<<<dim3(16,32),tb,0,stream>>>(Wv+(size_t)l*H_*KVD, WvTh, WvTl, H_, KVD, 0,0);
    k_transpose<<<dim3(32,32),tb,0,stream>>>(Wo+(size_t)l*NHD*H_, WoTh, WoTl, NHD, H_, 0,0);
    k_transpose<<<dim3(64,32,4),tb,0,stream>>>(Wg+(size_t)l*4*H_*I_, WgTh, WgTl, H_, I_, (long)H_*I_, (long)I_*H_);
    k_transpose<<<dim3(64,32,4),tb,0,stream>>>(Wu+(size_t)l*4*H_*I_, WuTh, WuTl, H_, I_, (long)H_*I_, (long)I_*H_);
    k_transpose<<<dim3(32,64,4),tb,0,stream>>>(Wd+(size_t)l*4*I_*H_, WdTh, WdTl, I_, H_, (long)I_*H_, (long)H_*I_);

    k_rms<<<T_/4,256,0,stream>>>(h, ln1+(size_t)l*H_, x);

    // QKV projections, split precision, fp32 outputs
    k_gemm<128,128,2,2,true,1,0><<<dim3(16,8,1),256,0,stream>>>(x, WqTh, WqTl, q, nullptr, H_, H_,H_,NHD, 0,0,1,0, 1.f,0);
    k_gemm<128,128,2,2,true,1,0><<<dim3(16,4,1),256,0,stream>>>(x, WkTh, WkTl, kf, nullptr, H_, H_,H_,KVD, 0,0,1,0, 1.f,0);
    k_gemm<128,128,2,2,true,5,0><<<dim3(16,4,1),256,0,stream>>>(x, WvTh, WvTl, vT, nullptr, H_, H_,H_,KVD, 0,0,1,0, 0.f,0);
    k_split<<<1024,256,0,stream>>>(kf, khi, klo);
    k_split<<<1024,256,0,stream>>>(vT, vthi, vtlo);

    for(int c=0;c<4;c++){
      int b = c>>1, qb=(c&1)*8, kb=qb>>1;
      const float* Aq = q + (size_t)b*S_*NHD + (size_t)qb*64;
      const u16* Bkh = khi + (size_t)b*S_*KVD + (size_t)kb*64;
      const u16* Bkl = klo + (size_t)b*S_*KVD + (size_t)kb*64;
      k_gemm<128,128,2,2,true,1,1><<<dim3(8,8,8),256,0,stream>>>(Aq, Bkh, Bkl, sc, nullptr, 64, NHD, KVD, S_, 64, 64, 2, (long)S_*S_, 0.125f, 0);
      k_softmax<<<dim3(256,8),256,0,stream>>>(sc);
      const u16* Bvh = vthi + (size_t)b*S_*KVD + (size_t)kb*64*S_;
      const u16* Bvl = vtlo + (size_t)b*S_*KVD + (size_t)kb*64*S_;
      float* Co = o + (size_t)b*S_*NHD + (size_t)qb*64;
      k_gemm<128,64,2,2,true,1,2><<<dim3(8,1,8),256,0,stream>>>(sc, Bvh, Bvl, Co, nullptr, S_, S_, S_, NHD, (long)S_*S_, (long)64*S_, 2, 64, 1.f, 0);
    }

    // o @ Wo += h
    k_gemm<128,128,2,2,true,2,0><<<dim3(16,8,1),256,0,stream>>>(o, WoTh, WoTl, h, nullptr, NHD, NHD,NHD,H_, 0,0,1,0, 0.f,0);

    k_router<<<T_/4,256,0,stream>>>(h, ln2+(size_t)l*H_, gate+(size_t)l*H_*4, comb);
    k_rms<<<T_/4,256,0,stream>>>(h, ln2+(size_t)l*H_, x);

    for(int e=0;e<4;e++){
      size_t eo = (size_t)e*H_*I_;
      k_gemm<128,128,2,2,true,1,0><<<dim3(16,16,1),256,0,stream>>>(x, WuTh+eo, WuTl+eo, gu, nullptr, H_, H_,H_,I_, 0,0,1,0, 1.f,0);
      k_gemm<128,128,2,2,true,3,0><<<dim3(16,16,1),256,0,stream>>>(x, WgTh+eo, WgTl+eo, gu, gu, H_, H_,H_,I_, 0,0,1,0, 0.f,0);
      k_gemm<128,128,2,2,true,4,0><<<dim3(16,8,1),256,0,stream>>>(gu, WdTh+eo, WdTl+eo, h, comb, I_, I_,I_,H_, 0,0,1,0, 0.f,e);
    }
  }

  k_rms<<<T_/4,256,0,stream>>>(h, normw, x);
  k_transpose<<<dim3(1000,32),tb,0,stream>>>(lmh, wp, nullptr, H_, V_, 0,0);
  k_gemm<128,128,2,2,false,1,0><<<dim3(16,250,1),256,0,stream>>>(x, wp, nullptr, (float*)d_out, nullptr, H_, H_,H_,V_, 0,0,1,0, 1.f,0);
}